// Round 12
// baseline (154.241 us; speedup 1.0000x reference)
//
#include <hip/hip_runtime.h>
#include <hip/hip_fp16.h>

// PQ sim: sim = decode(x) @ decode(tgt)^T via f16 GEMM (K=512).
// R12: persistent GEMM (R10) with CORRECTED FIFO vmcnt ledger.
// 256 blocks (1/CU) x 8 tiles (256x128, BK=64, 8 waves 4Mx2N). Ring-of-3 LDS
// runs continuously across tiles; tile T's stores interleaved 8/step into
// tile T+1's K-loop. KEY FIX vs R10: per step issue [6 stage loads] BEFORE
// [8 stores] (sched_barrier-pinned), so the boundary VMW completes exactly
// the oldest loads while stores stay in flight (vmcnt is FIFO, m135).
// VMW ramp: 6 (T0, no stores) -> 14 (T1 step0) -> 22 steady.

#define D_FULL 512
#define M_SUB 64
#define KSUB 256
#define DSUB 8
#define KP 512

typedef _Float16 f16x8 __attribute__((ext_vector_type(8)));
typedef float f32x4 __attribute__((ext_vector_type(4)));

static __device__ __forceinline__ unsigned int pack2h(float f0, float f1) {
  _Float16 h0 = (_Float16)f0, h1 = (_Float16)f1;
  unsigned short u0, u1;
  __builtin_memcpy(&u0, &h0, 2);
  __builtin_memcpy(&u1, &h1, 2);
  return (unsigned int)u0 | ((unsigned int)u1 << 16);
}

// ---------------- encode + decode queries into A' (f16), Q=4 ----------------
__global__ void encode_kernel(const float* __restrict__ x,
                              const float* __restrict__ cen,
                              unsigned short* __restrict__ Ap) {
  __shared__ float cs[KSUB][DSUB];
  __shared__ float n2[KSUB];
  const int t = threadIdx.x;
  const int s = blockIdx.x;
  const int i0 = blockIdx.y * 1024 + t;

  const float* cp = cen + ((size_t)s * KSUB + t) * DSUB;
  float4 c0 = *(const float4*)cp;
  float4 c1 = *(const float4*)(cp + 4);
  *(float4*)&cs[t][0] = c0;
  *(float4*)&cs[t][4] = c1;
  n2[t] = c0.x * c0.x + c0.y * c0.y + c0.z * c0.z + c0.w * c0.w +
          c1.x * c1.x + c1.y * c1.y + c1.z * c1.z + c1.w * c1.w;
  __syncthreads();

  float xq[4][8];
#pragma unroll
  for (int q = 0; q < 4; ++q) {
    const float* xp = x + (size_t)(i0 + q * 256) * D_FULL + s * DSUB;
    *(float4*)&xq[q][0] = *(const float4*)xp;
    *(float4*)&xq[q][4] = *(const float4*)(xp + 4);
  }

  float best[4] = {1e30f, 1e30f, 1e30f, 1e30f};
  int bk[4] = {0, 0, 0, 0};
#pragma unroll 4
  for (int k = 0; k < KSUB; ++k) {
    float c[8];
    *(float4*)&c[0] = *(const float4*)&cs[k][0];
    *(float4*)&c[4] = *(const float4*)&cs[k][4];
    const float nn = n2[k];
#pragma unroll
    for (int q = 0; q < 4; ++q) {
      float dot = 0.f;
#pragma unroll
      for (int d = 0; d < 8; ++d) dot += c[d] * xq[q][d];
      float dis = nn - 2.0f * dot;
      if (dis < best[q]) { best[q] = dis; bk[q] = k; }  // strict < = numpy tie
    }
  }

#pragma unroll
  for (int q = 0; q < 4; ++q) {
    const int b = bk[q];
    uint4 hv;
    hv.x = pack2h(cs[b][0], cs[b][1]);
    hv.y = pack2h(cs[b][2], cs[b][3]);
    hv.z = pack2h(cs[b][4], cs[b][5]);
    hv.w = pack2h(cs[b][6], cs[b][7]);
    *(uint4*)(Ap + (size_t)(i0 + q * 256) * KP + s * DSUB) = hv;
  }
}

// ---------------- decode targets into B' (f16) ----------------
__global__ void decode_tgt(const int* __restrict__ tgt,
                           const float* __restrict__ cen,
                           unsigned short* __restrict__ Bp) {
  int g = blockIdx.x * 256 + threadIdx.x;
  int j = g >> 6, s = g & 63;
  int k = tgt[g];
  const float* c = cen + ((size_t)s * KSUB + k) * DSUB;
  float4 v0 = *(const float4*)c;
  float4 v1 = *(const float4*)(c + 4);
  uint4 hv;
  hv.x = pack2h(v0.x, v0.y);
  hv.y = pack2h(v0.z, v0.w);
  hv.z = pack2h(v1.x, v1.y);
  hv.w = pack2h(v1.z, v1.w);
  *(uint4*)(Bp + (size_t)j * KP + s * DSUB) = hv;
}

// ---------------- persistent GEMM ----------------
#define GLL(SRC, DST)                                                          \
  __builtin_amdgcn_global_load_lds(                                            \
      (const __attribute__((address_space(1))) void*)(SRC),                    \
      (__attribute__((address_space(3))) void*)(DST), 16, 0, 0)

// Stage one BK=64 slice (A 32KB + B 16KB) into SLOT. 6 loads/thread.
// Linear LDS dest + inverse-swizzled global source (rule #21).
#define STAGE(AB, K0, SLOT)                                                    \
  do {                                                                         \
    unsigned short* as_ = &lds[(SLOT) * 24576];                                \
    unsigned short* bs_ = as_ + 16384;                                         \
    _Pragma("unroll") for (int it = 0; it < 4; ++it) {                         \
      int R = w * 32 + it * 8;                                                 \
      int r = R + (l >> 3);                                                    \
      int c = (l & 7) ^ (r & 7);                                               \
      GLL((AB) + (size_t)r * KP + (K0) + c * 8, as_ + R * 64 + l * 8);         \
    }                                                                          \
    _Pragma("unroll") for (int it = 0; it < 2; ++it) {                         \
      int R = w * 16 + it * 8;                                                 \
      int r = R + (l >> 3);                                                    \
      int c = (l & 7) ^ (r & 7);                                               \
      GLL(Bb + (size_t)r * KP + (K0) + c * 8, bs_ + R * 64 + l * 8);           \
    }                                                                          \
  } while (0)

// Consume one K-slice from SLOT: 16 ds_read_b128 + 32 MFMA per wave.
#define COMPUTE(SLOT, AC)                                                      \
  do {                                                                         \
    const unsigned short* as_ = &lds[(SLOT) * 24576];                          \
    const unsigned short* bs_ = as_ + 16384;                                   \
    _Pragma("unroll") for (int ks = 0; ks < 2; ++ks) {                         \
      f16x8 a_[4], b_[4];                                                      \
      int kq = ks * 4 + (l >> 4);                                              \
      _Pragma("unroll") for (int i2 = 0; i2 < 4; ++i2) {                       \
        int row = wm * 64 + i2 * 16 + (l & 15);                                \
        a_[i2] = *(const f16x8*)&as_[row * 64 + ((kq ^ (row & 7)) * 8)];       \
      }                                                                        \
      _Pragma("unroll") for (int j2 = 0; j2 < 4; ++j2) {                       \
        int row = wn * 64 + j2 * 16 + (l & 15);                                \
        b_[j2] = *(const f16x8*)&bs_[row * 64 + ((kq ^ (row & 7)) * 8)];       \
      }                                                                        \
      __builtin_amdgcn_s_setprio(1);                                           \
      _Pragma("unroll") for (int i2 = 0; i2 < 4; ++i2)                         \
          _Pragma("unroll") for (int j2 = 0; j2 < 4; ++j2) AC[i2][j2] =        \
          __builtin_amdgcn_mfma_f32_16x16x32_f16(a_[i2], b_[j2], AC[i2][j2],   \
                                                 0, 0, 0);                     \
      __builtin_amdgcn_s_setprio(0);                                           \
    }                                                                          \
  } while (0)

#define VMW_(N) asm volatile("s_waitcnt vmcnt(" #N ")" ::: "memory")
#define VMW(N) VMW_(N)
#define BAR() __builtin_amdgcn_s_barrier()

// Store chunk s (8 scalars) of the PREVIOUS tile's acc. Static indexing.
#define STREAL(AS, s, CP)                                                      \
  {                                                                            \
    _Pragma("unroll") for (int jo = 0; jo < 2; ++jo)                           \
        _Pragma("unroll") for (int r = 0; r < 4; ++r)(CP)[                     \
            (size_t)(((s) >> 1) * 16 + r) * Nt + (((s)&1) * 2 + jo) * 16] =    \
            AS[(s) >> 1][((s)&1) * 2 + jo][r];                                 \
  }
#define STNONE(AS, s, CP)

#define ZERO(AC)                                                               \
  {                                                                            \
    _Pragma("unroll") for (int i = 0; i < 4; ++i)                              \
        _Pragma("unroll") for (int j = 0; j < 4; ++j) AC[i][j] =               \
        (f32x4){0.f, 0.f, 0.f, 0.f};                                           \
  }

// One K-step: [stage slice t+2: 6 loads][fence][8 stores of prev tile]
// [compute slice t][VMW][BAR]. Loads BEFORE stores => the boundary VMW
// completes the oldest loads without waiting on any younger store.
#define TSTEP(s, AC, AS, STX, AB, K0, CP, VMN)                                 \
  {                                                                            \
    int ss_ = sc + 2;                                                          \
    if (ss_ > 2) ss_ -= 3;                                                     \
    STAGE(AB, K0, ss_);                                                        \
  }                                                                            \
  __builtin_amdgcn_sched_barrier(0);                                           \
  STX(AS, s, CP);                                                              \
  COMPUTE(sc, AC);                                                             \
  VMW(VMN);                                                                    \
  BAR();                                                                       \
  sc = (sc == 2) ? 0 : sc + 1;

// One tile = 8 K-steps; steps 6,7 stage the NEXT tile's slices 0,1.
#define TBODY(AC, AS, STX, ABC, ABN, CP, V0, VR)                               \
  TSTEP(0, AC, AS, STX, ABC, 128, CP, V0)                                      \
  TSTEP(1, AC, AS, STX, ABC, 192, CP, VR)                                      \
  TSTEP(2, AC, AS, STX, ABC, 256, CP, VR)                                      \
  TSTEP(3, AC, AS, STX, ABC, 320, CP, VR)                                      \
  TSTEP(4, AC, AS, STX, ABC, 384, CP, VR)                                      \
  TSTEP(5, AC, AS, STX, ABC, 448, CP, VR)                                      \
  TSTEP(6, AC, AS, STX, ABN, 0, CP, VR)                                        \
  TSTEP(7, AC, AS, STX, ABN, 64, CP, VR)

__global__ __launch_bounds__(512, 2) void gemm_nt(
    const unsigned short* __restrict__ A, const unsigned short* __restrict__ B,
    float* __restrict__ C, int Nt) {
  __shared__ unsigned short lds[3 * 24576];  // 144 KB ring-of-3
  const int tid = threadIdx.x;
  const int w = tid >> 6, l = tid & 63;
  const int wm = w >> 1, wn = w & 1;

  // XCD-pinned persistent mapping: 256 blocks; xcd owns bn [xcd*16,+16).
  const int bid = blockIdx.x;
  const int xcd = bid & 7;
  const int j = bid >> 3;              // 0..31
  const int bn = xcd * 16 + (j & 15);  // 0..127
  const int bmset = j >> 4;            // 0..1

  const unsigned short* Ab0 = A + (size_t)(bmset * 8) * 256 * KP;
  const unsigned short* Bb = B + (size_t)bn * 128 * KP;
  const size_t TSA = (size_t)256 * KP;
  const size_t CADV = (size_t)256 * Nt;

  float* Cp = C +
              ((size_t)(bmset * 8) * 256 + wm * 64 + (l >> 4) * 4) * Nt +
              bn * 128 + wn * 64 + (l & 15);
  float* cst = Cp;
  const unsigned short* abc = Ab0;

  f32x4 accE[4][4], accO[4][4];
  int sc = 0;

  // Prologue: slices 0,1; drain slice 0 (queue 12 -> complete oldest 6).
  STAGE(Ab0, 0, 0);
  STAGE(Ab0, 64, 1);
  VMW(6);
  BAR();

  // T0: compute accE, no stores. VMW(6): younger = stage(t+2) only.
  ZERO(accE);
  TBODY(accE, accO, STNONE, abc, abc + TSA, cst, 6, 6)
  abc += TSA;
  // T1: compute accO, store T0. Ramp: step0 VMW(14) (=6 loads + 8 stores
  // younger than needed slice), steady VMW(22) (=8+6+8).
  ZERO(accO);
  TBODY(accO, accE, STREAL, abc, abc + TSA, cst, 14, 22)
  abc += TSA;
  cst += CADV;

  // T2..T7 as pairs (acc ping-pong, static indexing). Steady VMW(22).
  for (int p = 1; p < 4; ++p) {
    ZERO(accE);
    TBODY(accE, accO, STREAL, abc, abc + TSA, cst, 22, 22)
    abc += TSA;
    cst += CADV;
    const unsigned short* abn2 = (p == 3) ? abc : abc + TSA;  // tail re-stage
    ZERO(accO);
    TBODY(accO, accE, STREAL, abc, abn2, cst, 22, 22)
    abc += TSA;
    cst += CADV;
  }

  // Final: store T7 (accO). cst = Cp + 7*CADV.
#pragma unroll
  for (int i2 = 0; i2 < 4; ++i2)
#pragma unroll
    for (int j2 = 0; j2 < 4; ++j2)
#pragma unroll
      for (int r = 0; r < 4; ++r)
        cst[(size_t)(i2 * 16 + r) * Nt + j2 * 16] = accO[i2][j2][r];
}

extern "C" void kernel_launch(void* const* d_in, const int* in_sizes, int n_in,
                              void* d_out, int out_size, void* d_ws, size_t ws_size,
                              hipStream_t stream) {
  const float* x = (const float*)d_in[0];    // [n, 512]
  const float* cen = (const float*)d_in[1];  // [64, 256, 8]
  const int* tgt = (const int*)d_in[2];      // [m, 64]
  float* out = (float*)d_out;                // [n, m]
  const int n = in_sizes[0] / D_FULL;        // 4096
  const int m = in_sizes[2] / M_SUB;         // 16384

  unsigned short* Ap = (unsigned short*)d_ws;  // [n, 512] f16
  unsigned short* Bp = Ap + (size_t)n * KP;    // [m, 512] f16

  encode_kernel<<<dim3(M_SUB, n / 1024), 256, 0, stream>>>(x, cen, Ap);
  decode_tgt<<<dim3((m * M_SUB) / 256), 256, 0, stream>>>(tgt, cen, Bp);
  gemm_nt<<<dim3(256), 512, 0, stream>>>(Ap, Bp, out, m);
}

// Round 13
// 137.314 us; speedup vs baseline: 1.1233x; 1.1233x over previous
//
#include <hip/hip_runtime.h>
#include <hip/hip_fp16.h>

// PQ sim: sim = decode(x) @ decode(tgt)^T via f16 GEMM (K=512).
// R13: GEMM at BM=128 BN=256 BK=32, 4 waves (1Mx4N, wave tile 128x64),
// double-buffered LDS 48 KB -> 2 blocks/CU so one block's epilogue/ramp
// overlaps the sibling's compute (cross-block TLP; R7 retried at the
// right geometry). Plain __syncthreads 2-phase, XOR chunk swizzle (T2),
// setprio (T5), XCD-pinned supertile mapping. Encode Q=4 / decode as R9.

#define D_FULL 512
#define M_SUB 64
#define KSUB 256
#define DSUB 8
#define KP 512

typedef _Float16 f16x8 __attribute__((ext_vector_type(8)));
typedef float f32x4 __attribute__((ext_vector_type(4)));

static __device__ __forceinline__ unsigned int pack2h(float f0, float f1) {
  _Float16 h0 = (_Float16)f0, h1 = (_Float16)f1;
  unsigned short u0, u1;
  __builtin_memcpy(&u0, &h0, 2);
  __builtin_memcpy(&u1, &h1, 2);
  return (unsigned int)u0 | ((unsigned int)u1 << 16);
}

// ---------------- encode + decode queries into A' (f16), Q=4 ----------------
__global__ void encode_kernel(const float* __restrict__ x,
                              const float* __restrict__ cen,
                              unsigned short* __restrict__ Ap) {
  __shared__ float cs[KSUB][DSUB];
  __shared__ float n2[KSUB];
  const int t = threadIdx.x;
  const int s = blockIdx.x;
  const int i0 = blockIdx.y * 1024 + t;

  const float* cp = cen + ((size_t)s * KSUB + t) * DSUB;
  float4 c0 = *(const float4*)cp;
  float4 c1 = *(const float4*)(cp + 4);
  *(float4*)&cs[t][0] = c0;
  *(float4*)&cs[t][4] = c1;
  n2[t] = c0.x * c0.x + c0.y * c0.y + c0.z * c0.z + c0.w * c0.w +
          c1.x * c1.x + c1.y * c1.y + c1.z * c1.z + c1.w * c1.w;
  __syncthreads();

  float xq[4][8];
#pragma unroll
  for (int q = 0; q < 4; ++q) {
    const float* xp = x + (size_t)(i0 + q * 256) * D_FULL + s * DSUB;
    *(float4*)&xq[q][0] = *(const float4*)xp;
    *(float4*)&xq[q][4] = *(const float4*)(xp + 4);
  }

  float best[4] = {1e30f, 1e30f, 1e30f, 1e30f};
  int bk[4] = {0, 0, 0, 0};
#pragma unroll 4
  for (int k = 0; k < KSUB; ++k) {
    float c[8];
    *(float4*)&c[0] = *(const float4*)&cs[k][0];
    *(float4*)&c[4] = *(const float4*)&cs[k][4];
    const float nn = n2[k];
#pragma unroll
    for (int q = 0; q < 4; ++q) {
      float dot = 0.f;
#pragma unroll
      for (int d = 0; d < 8; ++d) dot += c[d] * xq[q][d];
      float dis = nn - 2.0f * dot;
      if (dis < best[q]) { best[q] = dis; bk[q] = k; }  // strict < = numpy tie
    }
  }

#pragma unroll
  for (int q = 0; q < 4; ++q) {
    const int b = bk[q];
    uint4 hv;
    hv.x = pack2h(cs[b][0], cs[b][1]);
    hv.y = pack2h(cs[b][2], cs[b][3]);
    hv.z = pack2h(cs[b][4], cs[b][5]);
    hv.w = pack2h(cs[b][6], cs[b][7]);
    *(uint4*)(Ap + (size_t)(i0 + q * 256) * KP + s * DSUB) = hv;
  }
}

// ---------------- decode targets into B' (f16) ----------------
__global__ void decode_tgt(const int* __restrict__ tgt,
                           const float* __restrict__ cen,
                           unsigned short* __restrict__ Bp) {
  int g = blockIdx.x * 256 + threadIdx.x;
  int j = g >> 6, s = g & 63;
  int k = tgt[g];
  const float* c = cen + ((size_t)s * KSUB + k) * DSUB;
  float4 v0 = *(const float4*)c;
  float4 v1 = *(const float4*)(c + 4);
  uint4 hv;
  hv.x = pack2h(v0.x, v0.y);
  hv.y = pack2h(v0.z, v0.w);
  hv.z = pack2h(v1.x, v1.y);
  hv.w = pack2h(v1.z, v1.w);
  *(uint4*)(Bp + (size_t)j * KP + s * DSUB) = hv;
}

// ---------------- GEMM: C[n,m] = A'[n,KP] * B'[m,KP]^T ----------------
// Buffer (24 KB): A 128x32 f16 (8 KB) + B 256x32 f16 (16 KB). Row = 64 B =
// 4 chunks of 16 B. Phys chunk p at row r holds logical chunk p^(r&3)
// (stage: linear dest + inverse-swizzled global source, rule #21; read
// XORs back -> 4-way residual on b128, acceptable: LDS-read << MFMA time).
#define GLL(SRC, DST)                                                          \
  __builtin_amdgcn_global_load_lds(                                            \
      (const __attribute__((address_space(1))) void*)(SRC),                    \
      (__attribute__((address_space(3))) void*)(DST), 16, 0, 0)

#define STAGE(K0, BUF)                                                         \
  do {                                                                         \
    unsigned short* as_ = lds + (BUF) * 12288;                                 \
    unsigned short* bs_ = as_ + 4096;                                          \
    _Pragma("unroll") for (int L = 0; L < 2; ++L) {                            \
      int r = L * 64 + (tid >> 2);                                             \
      int c = (tid & 3) ^ (r & 3);                                             \
      GLL(Ab + (size_t)r * KP + (K0) + c * 8, as_ + L * 2048 + tid * 8);       \
    }                                                                          \
    _Pragma("unroll") for (int L = 0; L < 4; ++L) {                            \
      int r = L * 64 + (tid >> 2);                                             \
      int c = (tid & 3) ^ (r & 3);                                             \
      GLL(Bb + (size_t)r * KP + (K0) + c * 8, bs_ + L * 2048 + tid * 8);       \
    }                                                                          \
  } while (0)

// One BK=32 step from BUF: 12 ds_read_b128 + 32 MFMA per wave.
#define COMPUTE(BUF)                                                           \
  do {                                                                         \
    const unsigned short* as_ = lds + (BUF) * 12288;                           \
    const unsigned short* bs_ = as_ + 4096;                                    \
    f16x8 a_[8], b_[4];                                                        \
    _Pragma("unroll") for (int i2 = 0; i2 < 8; ++i2) {                         \
      int row = i2 * 16 + l16;                                                 \
      a_[i2] = *(const f16x8*)&as_[row * 32 + ((kq ^ (row & 3)) * 8)];         \
    }                                                                          \
    _Pragma("unroll") for (int j2 = 0; j2 < 4; ++j2) {                         \
      int row = wn * 64 + j2 * 16 + l16;                                       \
      b_[j2] = *(const f16x8*)&bs_[row * 32 + ((kq ^ (row & 3)) * 8)];         \
    }                                                                          \
    __builtin_amdgcn_s_setprio(1);                                             \
    _Pragma("unroll") for (int i2 = 0; i2 < 8; ++i2)                           \
        _Pragma("unroll") for (int j2 = 0; j2 < 4; ++j2) acc[i2][j2] =         \
        __builtin_amdgcn_mfma_f32_16x16x32_f16(a_[i2], b_[j2], acc[i2][j2],    \
                                               0, 0, 0);                       \
    __builtin_amdgcn_s_setprio(0);                                             \
  } while (0)

__global__ __launch_bounds__(256, 2) void gemm_nt(
    const unsigned short* __restrict__ A, const unsigned short* __restrict__ B,
    float* __restrict__ C, int Nt) {
  __shared__ unsigned short lds[2 * 12288];  // 48 KB dbuf -> 2 blocks/CU
  const int tid = threadIdx.x;
  const int wn = tid >> 6, l = tid & 63;  // 4 waves, 1M x 4N
  const int l16 = l & 15, kq = l >> 4;

  // XCD-pinned mapping: XCD x owns bn-stripe [x*8, x*8+8) (2 MB B,
  // L2-resident). Per XCD: 32bm x 8bn in 4bm x 8bn supertiles, bm-fastest;
  // the ~64 concurrent blocks/XCD span <=8bm x 8bn: 1 MB A + 2 MB B in L2.
  const int bid = blockIdx.x;
  const int xcd = bid & 7;
  const int idx = bid >> 3;                      // 0..255 per XCD
  const int sup = idx >> 5, loc = idx & 31;
  const int bm = sup * 4 + (loc & 3);            // 0..31
  const int bn = xcd * 8 + ((loc >> 2) & 7);     // 0..63

  const unsigned short* Ab = A + (size_t)bm * 128 * KP;
  const unsigned short* Bb = B + (size_t)bn * 256 * KP;

  f32x4 acc[8][4] = {};

  // 2-phase dbuf: stage next while computing current; __syncthreads drains.
  STAGE(0, 0);
  __syncthreads();
  STAGE(32, 1);  COMPUTE(0); __syncthreads();   // t=0
  STAGE(64, 0);  COMPUTE(1); __syncthreads();   // t=1
  STAGE(96, 1);  COMPUTE(0); __syncthreads();   // t=2
  STAGE(128, 0); COMPUTE(1); __syncthreads();   // t=3
  STAGE(160, 1); COMPUTE(0); __syncthreads();   // t=4
  STAGE(192, 0); COMPUTE(1); __syncthreads();   // t=5
  STAGE(224, 1); COMPUTE(0); __syncthreads();   // t=6
  STAGE(256, 0); COMPUTE(1); __syncthreads();   // t=7
  STAGE(288, 1); COMPUTE(0); __syncthreads();   // t=8
  STAGE(320, 0); COMPUTE(1); __syncthreads();   // t=9
  STAGE(352, 1); COMPUTE(0); __syncthreads();   // t=10
  STAGE(384, 0); COMPUTE(1); __syncthreads();   // t=11
  STAGE(416, 1); COMPUTE(0); __syncthreads();   // t=12
  STAGE(448, 0); COMPUTE(1); __syncthreads();   // t=13
  STAGE(480, 1); COMPUTE(0); __syncthreads();   // t=14
  COMPUTE(1);                                    // t=15

  // Epilogue: C/D layout col=lane&15, row=(lane>>4)*4+reg (m89/m91).
  const int rb = bm * 128 + (l >> 4) * 4;
  const int cb = bn * 256 + wn * 64 + l16;
#pragma unroll
  for (int i2 = 0; i2 < 8; ++i2)
#pragma unroll
    for (int j2 = 0; j2 < 4; ++j2)
#pragma unroll
      for (int r = 0; r < 4; ++r)
        C[(size_t)(rb + i2 * 16 + r) * Nt + cb + j2 * 16] = acc[i2][j2][r];
}

extern "C" void kernel_launch(void* const* d_in, const int* in_sizes, int n_in,
                              void* d_out, int out_size, void* d_ws, size_t ws_size,
                              hipStream_t stream) {
  const float* x = (const float*)d_in[0];    // [n, 512]
  const float* cen = (const float*)d_in[1];  // [64, 256, 8]
  const int* tgt = (const int*)d_in[2];      // [m, 64]
  float* out = (float*)d_out;                // [n, m]
  const int n = in_sizes[0] / D_FULL;        // 4096
  const int m = in_sizes[2] / M_SUB;         // 16384

  unsigned short* Ap = (unsigned short*)d_ws;  // [n, 512] f16
  unsigned short* Bp = Ap + (size_t)n * KP;    // [m, 512] f16

  encode_kernel<<<dim3(M_SUB, n / 1024), 256, 0, stream>>>(x, cen, Ap);
  decode_tgt<<<dim3((m * M_SUB) / 256), 256, 0, stream>>>(tgt, cen, Bp);
  gemm_nt<<<dim3((n / 128) * (m / 256)), 256, 0, stream>>>(Ap, Bp, out, m);
}

// Round 14
// 112.462 us; speedup vs baseline: 1.3715x; 1.2210x over previous
//
#include <hip/hip_runtime.h>
#include <hip/hip_fp16.h>

// PQ sim: sim = decode(x) @ decode(tgt)^T via i8 GEMM (K=512, exact int32
// accumulate; global symmetric scale s = 127/max|cen| measured on device).
// R14: GEMM 256x256, BK=128 i8, 8 waves (2Mx4N), dbuf 128 KB, plain
// __syncthreads 2-phase (4 K-steps), XOR chunk swizzle (T2, rule #21),
// setprio (T5), XCD-pinned supertile mapping. Encode Q=4 exact-f32 argmin.

#define D_FULL 512
#define M_SUB 64
#define KSUB 256
#define DSUB 8
#define KPB 512  // bytes per row (512 i8)

typedef int i32x4 __attribute__((ext_vector_type(4)));

static __device__ __forceinline__ unsigned int pack4i8(float a, float b,
                                                       float c, float d,
                                                       float s) {
  int q0 = (int)rintf(a * s), q1 = (int)rintf(b * s);
  int q2 = (int)rintf(c * s), q3 = (int)rintf(d * s);
  return (unsigned int)(q0 & 0xff) | ((unsigned int)(q1 & 0xff) << 8) |
         ((unsigned int)(q2 & 0xff) << 16) | ((unsigned int)(q3 & 0xff) << 24);
}

// Reduce the 64 per-block partial maxes (written by max_kernel).
static __device__ __forceinline__ float scale_from(const float* part) {
  float m = 0.f;
#pragma unroll
  for (int i = 0; i < 64; ++i) m = fmaxf(m, part[i]);
  return 127.0f / m;
}

// ---------------- pass 0: per-block max|cen| (64 partials, no atomics) ----
__global__ void max_kernel(const float* __restrict__ cen,
                           float* __restrict__ part) {
  const int t = threadIdx.x;
  const int i = (blockIdx.x * 256 + t) * 8;
  float4 a = *(const float4*)(cen + i);
  float4 b = *(const float4*)(cen + i + 4);
  float m = fmaxf(fmaxf(fmaxf(fabsf(a.x), fabsf(a.y)),
                        fmaxf(fabsf(a.z), fabsf(a.w))),
                  fmaxf(fmaxf(fabsf(b.x), fabsf(b.y)),
                        fmaxf(fabsf(b.z), fabsf(b.w))));
  __shared__ float wm[4];
  for (int off = 32; off; off >>= 1) m = fmaxf(m, __shfl_down(m, off, 64));
  if ((t & 63) == 0) wm[t >> 6] = m;
  __syncthreads();
  if (t == 0)
    part[blockIdx.x] = fmaxf(fmaxf(wm[0], wm[1]), fmaxf(wm[2], wm[3]));
}

// ---------------- encode queries -> A' (i8), Q=4, exact f32 argmin ----------
__global__ void encode_kernel(const float* __restrict__ x,
                              const float* __restrict__ cen,
                              signed char* __restrict__ Ap,
                              const float* __restrict__ part) {
  __shared__ float cs[KSUB][DSUB];
  __shared__ float n2[KSUB];
  const int t = threadIdx.x;
  const int sub = blockIdx.x;
  const int i0 = blockIdx.y * 1024 + t;

  const float* cp = cen + ((size_t)sub * KSUB + t) * DSUB;
  float4 c0 = *(const float4*)cp;
  float4 c1 = *(const float4*)(cp + 4);
  *(float4*)&cs[t][0] = c0;
  *(float4*)&cs[t][4] = c1;
  n2[t] = c0.x * c0.x + c0.y * c0.y + c0.z * c0.z + c0.w * c0.w +
          c1.x * c1.x + c1.y * c1.y + c1.z * c1.z + c1.w * c1.w;
  __syncthreads();

  float xq[4][8];
#pragma unroll
  for (int q = 0; q < 4; ++q) {
    const float* xp = x + (size_t)(i0 + q * 256) * D_FULL + sub * DSUB;
    *(float4*)&xq[q][0] = *(const float4*)xp;
    *(float4*)&xq[q][4] = *(const float4*)(xp + 4);
  }

  float best[4] = {1e30f, 1e30f, 1e30f, 1e30f};
  int bk[4] = {0, 0, 0, 0};
#pragma unroll 4
  for (int k = 0; k < KSUB; ++k) {
    float c[8];
    *(float4*)&c[0] = *(const float4*)&cs[k][0];
    *(float4*)&c[4] = *(const float4*)&cs[k][4];
    const float nn = n2[k];
#pragma unroll
    for (int q = 0; q < 4; ++q) {
      float dot = 0.f;
#pragma unroll
      for (int d = 0; d < 8; ++d) dot += c[d] * xq[q][d];
      float dis = nn - 2.0f * dot;
      if (dis < best[q]) { best[q] = dis; bk[q] = k; }  // strict < = numpy tie
    }
  }

  const float s = scale_from(part);
#pragma unroll
  for (int q = 0; q < 4; ++q) {
    const int b = bk[q];
    uint2 v;
    v.x = pack4i8(cs[b][0], cs[b][1], cs[b][2], cs[b][3], s);
    v.y = pack4i8(cs[b][4], cs[b][5], cs[b][6], cs[b][7], s);
    *(uint2*)(Ap + (size_t)(i0 + q * 256) * KPB + sub * DSUB) = v;
  }
}

// ---------------- decode targets -> B' (i8) ----------------
__global__ void decode_tgt(const int* __restrict__ tgt,
                           const float* __restrict__ cen,
                           signed char* __restrict__ Bp,
                           const float* __restrict__ part) {
  int g = blockIdx.x * 256 + threadIdx.x;
  int j = g >> 6, sub = g & 63;
  int k = tgt[g];
  const float* c = cen + ((size_t)sub * KSUB + k) * DSUB;
  float4 v0 = *(const float4*)c;
  float4 v1 = *(const float4*)(c + 4);
  const float s = scale_from(part);
  uint2 v;
  v.x = pack4i8(v0.x, v0.y, v0.z, v0.w, s);
  v.y = pack4i8(v1.x, v1.y, v1.z, v1.w, s);
  *(uint2*)(Bp + (size_t)j * KPB + sub * DSUB) = v;
}

// ---------------- GEMM: C = (A'q . B'q^T) / s^2 ----------------
// Buffer (64 KB): A 256x128 i8 (32 KB) + B 256x128 i8 (32 KB). Row = 128 B =
// 8 chunks of 16 B. Phys chunk p at row r holds logical chunk p^(r&7)
// (stage: linear dest + inverse-swizzled global source, rule #21; read XORs
// back -> 2 rows/bank-group = free).
#define GLL(SRC, DST)                                                          \
  __builtin_amdgcn_global_load_lds(                                            \
      (const __attribute__((address_space(1))) void*)(SRC),                    \
      (__attribute__((address_space(3))) void*)(DST), 16, 0, 0)

#define STAGE(K0, BUF)                                                         \
  do {                                                                         \
    signed char* as_ = lds + (BUF)*65536;                                      \
    signed char* bs_ = as_ + 32768;                                            \
    _Pragma("unroll") for (int it = 0; it < 4; ++it) {                         \
      int r = it * 64 + (tid >> 3);                                            \
      int c = (tid & 7) ^ (r & 7);                                             \
      GLL(Ab + (size_t)r * KPB + (K0) + c * 16, as_ + it * 8192 + tid * 16);   \
    }                                                                          \
    _Pragma("unroll") for (int it = 0; it < 4; ++it) {                         \
      int r = it * 64 + (tid >> 3);                                            \
      int c = (tid & 7) ^ (r & 7);                                             \
      GLL(Bb + (size_t)r * KPB + (K0) + c * 16, bs_ + it * 8192 + tid * 16);   \
    }                                                                          \
  } while (0)

// One BK=128 step from BUF: 2 ks x {8 A-frags, 4 B-frags, 32 MFMA i8 K=64}.
#define COMPUTE(BUF)                                                           \
  do {                                                                         \
    const signed char* as_ = lds + (BUF)*65536;                                \
    const signed char* bs_ = as_ + 32768;                                      \
    _Pragma("unroll") for (int ks = 0; ks < 2; ++ks) {                         \
      const int kq = ks * 4 + (l >> 4);                                        \
      i32x4 a_[8], b_[4];                                                      \
      _Pragma("unroll") for (int i2 = 0; i2 < 8; ++i2) {                       \
        int row = wm * 128 + i2 * 16 + (l & 15);                               \
        a_[i2] = *(const i32x4*)&as_[row * 128 + ((kq ^ (row & 7)) * 16)];     \
      }                                                                        \
      _Pragma("unroll") for (int j2 = 0; j2 < 4; ++j2) {                       \
        int row = wn * 64 + j2 * 16 + (l & 15);                                \
        b_[j2] = *(const i32x4*)&bs_[row * 128 + ((kq ^ (row & 7)) * 16)];     \
      }                                                                        \
      __builtin_amdgcn_s_setprio(1);                                           \
      _Pragma("unroll") for (int i2 = 0; i2 < 8; ++i2)                         \
          _Pragma("unroll") for (int j2 = 0; j2 < 4; ++j2) acc[i2][j2] =       \
          __builtin_amdgcn_mfma_i32_16x16x64_i8(a_[i2], b_[j2], acc[i2][j2],   \
                                                0, 0, 0);                      \
      __builtin_amdgcn_s_setprio(0);                                           \
    }                                                                          \
  } while (0)

__global__ __launch_bounds__(512, 2) void gemm_i8(
    const signed char* __restrict__ A, const signed char* __restrict__ B,
    float* __restrict__ C, int Nt, const float* __restrict__ part) {
  __shared__ signed char lds[2 * 65536];  // 128 KB dbuf
  const int tid = threadIdx.x;
  const int w = tid >> 6, l = tid & 63;
  const int wm = w >> 2, wn = w & 3;  // 2M x 4N -> wave tile 128x64

  // XCD-pinned mapping: XCD x owns bn-stripe [x*8, x*8+8) (8 B-panels, 1 MB
  // i8, L2-resident). Within XCD walk 2bm x 8bn supertiles bm-fastest.
  const int bid = blockIdx.x;
  const int xcd = bid & 7;
  const int idx = bid >> 3;                   // 0..127 per XCD
  const int bm = (idx >> 4) * 2 + (idx & 1);  // 0..15
  const int bn = xcd * 8 + ((idx >> 1) & 7);  // 0..63

  const signed char* Ab = A + (size_t)bm * 256 * KPB;
  const signed char* Bb = B + (size_t)bn * 256 * KPB;

  i32x4 acc[8][4] = {};

  // 2-phase dbuf over 4 K-steps (BK=128 i8).
  STAGE(0, 0);
  __syncthreads();
  STAGE(128, 1); COMPUTE(0); __syncthreads();  // t=0
  STAGE(256, 0); COMPUTE(1); __syncthreads();  // t=1
  STAGE(384, 1); COMPUTE(0); __syncthreads();  // t=2
  COMPUTE(1);                                   // t=3

  // Epilogue: sim = acc * (max/127)^2. C/D layout col=lane&15,
  // row=(lane>>4)*4+reg (dtype-independent, m121-128).
  const float minv = 1.0f / scale_from(part);  // = max/127
  const float inv = minv * minv;
  const int rb = bm * 256 + wm * 128 + (l >> 4) * 4;
  const int cb = bn * 256 + wn * 64 + (l & 15);
#pragma unroll
  for (int i2 = 0; i2 < 8; ++i2)
#pragma unroll
    for (int j2 = 0; j2 < 4; ++j2)
#pragma unroll
      for (int r = 0; r < 4; ++r)
        C[(size_t)(rb + i2 * 16 + r) * Nt + cb + j2 * 16] =
            (float)acc[i2][j2][r] * inv;
}

extern "C" void kernel_launch(void* const* d_in, const int* in_sizes, int n_in,
                              void* d_out, int out_size, void* d_ws, size_t ws_size,
                              hipStream_t stream) {
  const float* x = (const float*)d_in[0];    // [n, 512]
  const float* cen = (const float*)d_in[1];  // [64, 256, 8]
  const int* tgt = (const int*)d_in[2];      // [m, 64]
  float* out = (float*)d_out;                // [n, m]
  const int n = in_sizes[0] / D_FULL;        // 4096
  const int m = in_sizes[2] / M_SUB;         // 16384

  signed char* Ap = (signed char*)d_ws;            // [n, 512] i8
  signed char* Bp = Ap + (size_t)n * KPB;          // [m, 512] i8
  float* part = (float*)(Bp + (size_t)m * KPB);    // [64] partial maxes

  max_kernel<<<dim3(64), 256, 0, stream>>>(cen, part);
  encode_kernel<<<dim3(M_SUB, n / 1024), 256, 0, stream>>>(x, cen, Ap, part);
  decode_tgt<<<dim3((m * M_SUB) / 256), 256, 0, stream>>>(tgt, cen, Bp, part);
  gemm_i8<<<dim3((n / 256) * (m / 256)), 512, 0, stream>>>(Ap, Bp, out, m, part);
}